// Round 1
// baseline (684.799 us; speedup 1.0000x reference)
//
#include <hip/hip_runtime.h>
#include <math.h>

#define T_SEQ  2048
#define C_DIM  2048
#define H_NUM  16
#define D_HEAD 128
#define MEM_N  1024
#define S_ALL  3072
#define QKV_N  6144

typedef __attribute__((ext_vector_type(4))) float f32x4;
typedef __attribute__((ext_vector_type(8))) short bf16x8;
typedef __attribute__((ext_vector_type(8))) unsigned short us8;

__device__ __forceinline__ unsigned short f2bf(float f) {
    unsigned int u = __float_as_uint(f);
    u = (u + 0x7fffu + ((u >> 16) & 1u)) >> 16;   // RNE
    return (unsigned short)u;
}

// async global->LDS, 16B per lane; lds ptr must be wave-uniform (HW adds lane*16)
__device__ __forceinline__ void gload_lds16(const void* g, void* l) {
    __builtin_amdgcn_global_load_lds((const __attribute__((address_space(1))) void*)g,
                                     (__attribute__((address_space(3))) void*)l, 16, 0, 0);
}

// ===== transpose W: [K=2048, N] fp32 -> Th [N][2048] bf16 (RNE) =====
// 2-term hi/lo GEMM keeps A exact, B rounded -> only hi needed.
__global__ __launch_bounds__(256, 2)
void split_w_t(const float* __restrict__ W, unsigned short* __restrict__ Th, int N)
{
    __shared__ float tile[64][68];
    const int tid = threadIdx.x;
    const int n0 = blockIdx.x << 6, k0 = blockIdx.y << 6;
    const int r = tid >> 2, c4 = (tid & 3) << 4;
    const float* src = W + (size_t)(k0 + r) * N + n0 + c4;
#pragma unroll
    for (int i = 0; i < 4; ++i)
        *(float4*)&tile[r][c4 + (i << 2)] = *(const float4*)(src + (i << 2));
    __syncthreads();
    unsigned int hi[8];
#pragma unroll
    for (int e = 0; e < 8; ++e) {
        const unsigned int h0 = f2bf(tile[c4 + 2 * e][r]);
        const unsigned int h1 = f2bf(tile[c4 + 2 * e + 1][r]);
        hi[e] = h0 | (h1 << 16);
    }
    unsigned short* dh = Th + (size_t)(n0 + r) * 2048 + k0 + c4;
    *(uint4*)dh       = make_uint4(hi[0], hi[1], hi[2], hi[3]);
    *(uint4*)(dh + 8) = make_uint4(hi[4], hi[5], hi[6], hi[7]);
}

// ===== memory bank: fp32 [1024,2048] -> memb bf16 [1024,2048] + memt bf16 [2048,1024]
__global__ __launch_bounds__(256, 2)
void split_mem_kernel(const float* __restrict__ mem, unsigned short* __restrict__ memb,
                      unsigned short* __restrict__ memt)
{
    __shared__ float tile[64][68];
    const int tid = threadIdx.x;
    const int c0 = blockIdx.x << 6, s0 = blockIdx.y << 6;
    const int r = tid >> 2, c4 = (tid & 3) << 4;
    const float* src = mem + (size_t)(s0 + r) * 2048 + c0 + c4;
    unsigned short* db = memb + (size_t)(s0 + r) * 2048 + c0 + c4;
#pragma unroll
    for (int i = 0; i < 4; ++i) {
        const float4 v = *(const float4*)(src + (i << 2));
        *(float4*)&tile[r][c4 + (i << 2)] = v;
        ushort4 o;
        o.x = f2bf(v.x); o.y = f2bf(v.y); o.z = f2bf(v.z); o.w = f2bf(v.w);
        *(ushort4*)(db + (i << 2)) = o;
    }
    __syncthreads();
    unsigned short* dt = memt + (size_t)(c0 + r) * 1024 + s0 + c4;
#pragma unroll
    for (int i = 0; i < 4; ++i) {
        ushort4 o;
        o.x = f2bf(tile[c4 + (i << 2) + 0][r]);
        o.y = f2bf(tile[c4 + (i << 2) + 1][r]);
        o.z = f2bf(tile[c4 + (i << 2) + 2][r]);
        o.w = f2bf(tile[c4 + (i << 2) + 3][r]);
        *(ushort4*)(dt + (i << 2)) = o;
    }
}

// ===== Vr [b,h,2048,128] bf16 -> Vrt [b,h,128,2048] bf16 =====
__global__ __launch_bounds__(256, 2)
void transpose_v_kernel(const unsigned short* __restrict__ Vr, unsigned short* __restrict__ Vrt)
{
    __shared__ unsigned short Vtmp[64 * 136];
    const int tid = threadIdx.x;
    const int s0 = (int)blockIdx.x << 6;
    const int h = blockIdx.y, b = blockIdx.z;
    const size_t bho = (size_t)(b * H_NUM + h) * (2048 * 128);
    const int sr = tid >> 2, ch = (tid & 3) << 5;
    const unsigned short* vp = Vr + bho + (size_t)(s0 + sr) * 128 + ch;
#pragma unroll
    for (int i = 0; i < 4; ++i)
        *(float4*)&Vtmp[sr * 136 + ch + (i << 3)] = *(const float4*)(vp + (i << 3));
    __syncthreads();
    const int d = tid >> 1, half = tid & 1;
    unsigned short* vd = Vrt + bho + (size_t)d * 2048 + s0 + (half << 5);
#pragma unroll
    for (int c = 0; c < 4; ++c) {
        us8 o;
#pragma unroll
        for (int j = 0; j < 8; ++j)
            o[j] = Vtmp[((half << 5) + (c << 3) + j) * 136 + d];
        *(us8*)(vd + (c << 3)) = o;
    }
}

// ===== GEMM1: qkv = x @ WqT^T + b, 2-term hi/lo MFMA; scatter to qb/Kr/Vr =====
__global__ __launch_bounds__(256, 3)
void gemm_qkv_mfma(const float* __restrict__ x,
                   const unsigned short* __restrict__ Bth,
                   const float* __restrict__ bias,
                   unsigned short* __restrict__ qb, unsigned short* __restrict__ Kr,
                   unsigned short* __restrict__ Vr)
{
    __shared__ unsigned short Ah[128 * 32], Al[128 * 32], Bh[128 * 32];
    const int tid = threadIdx.x;
    const int w = tid >> 6, lane = tid & 63, c16 = lane & 15, quad = lane >> 4;
    const int wm = w & 1, wn = w >> 1;
    const int bm = blockIdx.y << 7, bn = blockIdx.x << 7;

    const int ar = tid >> 1, ak = (tid & 1) << 4;
    const float* pA = x + (size_t)(bm + ar) * 2048 + ak;
    const int wofs = (tid >> 6) << 10;

    f32x4 acc[16];
#pragma unroll
    for (int i = 0; i < 16; ++i) acc[i] = (f32x4){0.f, 0.f, 0.f, 0.f};

    for (int kt = 0; kt < 2048; kt += 32) {
        float4 af[4];
#pragma unroll
        for (int i = 0; i < 4; ++i) af[i] = *(const float4*)(pA + kt + (i << 2));
        __syncthreads();
#pragma unroll
        for (int j = 0; j < 2; ++j) {
            const int c = (j << 8) + tid;
            const size_t go = (size_t)(bn + (c >> 2)) * 2048 + kt + ((c & 3) << 3);
            gload_lds16(Bth + go, (char*)Bh + (j << 12) + wofs);
        }
        // split A: hi truncated + lo residual (A represented exactly to ~2^-17)
        const float* f = (const float*)af;
        unsigned int hp[8], lp[8];
#pragma unroll
        for (int e = 0; e < 8; ++e) {
            const unsigned int u0 = __float_as_uint(f[2 * e]), u1 = __float_as_uint(f[2 * e + 1]);
            const float l0 = f[2 * e]     - __uint_as_float(u0 & 0xFFFF0000u);
            const float l1 = f[2 * e + 1] - __uint_as_float(u1 & 0xFFFF0000u);
            hp[e] = (u0 >> 16) | (u1 & 0xFFFF0000u);
            lp[e] = (__float_as_uint(l0) >> 16) | (__float_as_uint(l1) & 0xFFFF0000u);
        }
        *(uint4*)&Ah[ar * 32 + ak]     = make_uint4(hp[0], hp[1], hp[2], hp[3]);
        *(uint4*)&Ah[ar * 32 + ak + 8] = make_uint4(hp[4], hp[5], hp[6], hp[7]);
        *(uint4*)&Al[ar * 32 + ak]     = make_uint4(lp[0], lp[1], lp[2], lp[3]);
        *(uint4*)&Al[ar * 32 + ak + 8] = make_uint4(lp[4], lp[5], lp[6], lp[7]);
        __syncthreads();

        bf16x8 a_h[4], a_l[4];
#pragma unroll
        for (int mt = 0; mt < 4; ++mt) {
            const int ao = (wm * 64 + mt * 16 + c16) * 32 + quad * 8;
            a_h[mt] = *(const bf16x8*)&Ah[ao];
            a_l[mt] = *(const bf16x8*)&Al[ao];
        }
#pragma unroll
        for (int nt = 0; nt < 4; ++nt) {
            const int bo = (wn * 64 + nt * 16 + c16) * 32 + quad * 8;
            const bf16x8 b_h = *(const bf16x8*)&Bh[bo];
#pragma unroll
            for (int mt = 0; mt < 4; ++mt) {
                acc[mt * 4 + nt] = __builtin_amdgcn_mfma_f32_16x16x32_bf16(a_h[mt], b_h, acc[mt * 4 + nt], 0, 0, 0);
                acc[mt * 4 + nt] = __builtin_amdgcn_mfma_f32_16x16x32_bf16(a_l[mt], b_h, acc[mt * 4 + nt], 0, 0, 0);
            }
        }
    }

    const int cls = bn >> 11;
    const float scl = (cls == 0) ? 0.08838834764831845f : 1.0f;
    const int h = (bn & 2047) >> 7;
    float bv[4];
#pragma unroll
    for (int nt = 0; nt < 4; ++nt) bv[nt] = bias[bn + wn * 64 + nt * 16 + c16];
#pragma unroll
    for (int mt = 0; mt < 4; ++mt) {
#pragma unroll
        for (int r = 0; r < 4; ++r) {
            const int rg = bm + wm * 64 + mt * 16 + quad * 4 + r;
            unsigned short* dst;
            if (cls == 0) {
                dst = qb + (size_t)rg * 2048 + bn;
            } else {
                const int bb = rg >> 11, t = rg & 2047;
                dst = (cls == 1 ? Kr : Vr) + (size_t)(bb * H_NUM + h) * (2048 * 128) + (size_t)t * 128;
            }
#pragma unroll
            for (int nt = 0; nt < 4; ++nt)
                dst[wn * 64 + nt * 16 + c16] = f2bf((acc[mt * 4 + nt][r] + bv[nt]) * scl);
        }
    }
}

// ===== GEMM2: out = (attn_h+attn_l) @ WpT^T + b, 2-term hi/lo, fp32 out =====
__global__ __launch_bounds__(256, 3)
void gemm_proj_mfma(const unsigned short* __restrict__ Ahg, const unsigned short* __restrict__ Alg,
                    const unsigned short* __restrict__ Bth,
                    const float* __restrict__ bias, float* __restrict__ out)
{
    __shared__ unsigned short Ah[128 * 32], Al[128 * 32], Bh[128 * 32];
    const int tid = threadIdx.x;
    const int w = tid >> 6, lane = tid & 63, c16 = lane & 15, quad = lane >> 4;
    const int wm = w & 1, wn = w >> 1;
    const int bm = blockIdx.y << 7, bn = blockIdx.x << 7;
    const int wofs = (tid >> 6) << 10;

    f32x4 acc[16];
#pragma unroll
    for (int i = 0; i < 16; ++i) acc[i] = (f32x4){0.f, 0.f, 0.f, 0.f};

    for (int kt = 0; kt < 2048; kt += 32) {
        __syncthreads();
#pragma unroll
        for (int j = 0; j < 2; ++j) {
            const int c = (j << 8) + tid;
            const size_t ga = (size_t)(bm + (c >> 2)) * 2048 + kt + ((c & 3) << 3);
            const size_t gb = (size_t)(bn + (c >> 2)) * 2048 + kt + ((c & 3) << 3);
            gload_lds16(Ahg + ga, (char*)Ah + (j << 12) + wofs);
            gload_lds16(Alg + ga, (char*)Al + (j << 12) + wofs);
            gload_lds16(Bth + gb, (char*)Bh + (j << 12) + wofs);
        }
        __syncthreads();

        bf16x8 a_h[4], a_l[4];
#pragma unroll
        for (int mt = 0; mt < 4; ++mt) {
            const int ao = (wm * 64 + mt * 16 + c16) * 32 + quad * 8;
            a_h[mt] = *(const bf16x8*)&Ah[ao];
            a_l[mt] = *(const bf16x8*)&Al[ao];
        }
#pragma unroll
        for (int nt = 0; nt < 4; ++nt) {
            const int bo = (wn * 64 + nt * 16 + c16) * 32 + quad * 8;
            const bf16x8 b_h = *(const bf16x8*)&Bh[bo];
#pragma unroll
            for (int mt = 0; mt < 4; ++mt) {
                acc[mt * 4 + nt] = __builtin_amdgcn_mfma_f32_16x16x32_bf16(a_h[mt], b_h, acc[mt * 4 + nt], 0, 0, 0);
                acc[mt * 4 + nt] = __builtin_amdgcn_mfma_f32_16x16x32_bf16(a_l[mt], b_h, acc[mt * 4 + nt], 0, 0, 0);
            }
        }
    }

    float bv[4];
#pragma unroll
    for (int nt = 0; nt < 4; ++nt) bv[nt] = bias[bn + wn * 64 + nt * 16 + c16];
#pragma unroll
    for (int mt = 0; mt < 4; ++mt) {
#pragma unroll
        for (int r = 0; r < 4; ++r) {
            const int rg = bm + wm * 64 + mt * 16 + quad * 4 + r;
            float* dst = out + (size_t)rg * 2048 + bn + wn * 64 + c16;
#pragma unroll
            for (int nt = 0; nt < 4; ++nt)
                dst[nt * 16] = acc[mt * 4 + nt][r] + bv[nt];
        }
    }
}

// ============ MFMA flash attention — 8-wave restructure ============
// Same math/layout as the round-4 proven 4-wave kernel, but 512 threads:
// each of 8 waves owns 16 q-rows (qi dimension removed). Occupancy goal:
// 2 blocks/CU x 8 waves = 16 waves/CU (4/SIMD) — double the prior 8/CU.
// Per-thread register state ~halves (acc_o 32, qfrag 16, kf/vf 16) to fit
// the 128-VGPR budget 16 waves/CU requires -> no scratch spill.
// LDS unchanged: Ks[64*136] + Vts[128*72] + Ps[128*72] = 54,272 B.
__global__ __launch_bounds__(512, 4)
void attn_mfma_kernel(const unsigned short* __restrict__ qb,
                      const unsigned short* __restrict__ Kr,
                      const unsigned short* __restrict__ memb,
                      const unsigned short* __restrict__ Vrt,
                      const unsigned short* __restrict__ memt,
                      unsigned short* __restrict__ attn_h,
                      unsigned short* __restrict__ attn_l)
{
    __shared__ unsigned short lds[27136];
    unsigned short* Ks  = lds;            // 64*136  = 8704 u16
    unsigned short* Vts = lds + 8704;     // 128*72  = 9216 u16
    unsigned short* Ps  = lds + 17920;    // 128*72  = 9216 u16
    unsigned short* Os  = lds;            // overlay (Q stage / epilogue), 128*136

    const int tid = threadIdx.x;
    const int w = tid >> 6, lane = tid & 63;
    const int c16 = lane & 15, quad = lane >> 4;
    const int bx = blockIdx.x;
    const int h = blockIdx.y, b = blockIdx.z;
    // balance swizzle: co-resident pair (block i, i+256) gets qt x and 15-x
    const int qt = b ? bx : (15 - bx);
    const int t0 = qt << 7;               // 128-row q tile
    const int bT = b * T_SEQ;
    const int bh = b * H_NUM + h;

    const unsigned short* Krb = Kr + (size_t)bh * (2048 * 128);
    const unsigned short* Vrb = Vrt + (size_t)bh * (2048 * 128);

    // ---- stage Q through LDS (wave-private rows), load B-frags to regs ----
    bf16x8 qfrag[4];
    {
        const int row = tid >> 2, co = (tid & 3) << 5;
        const unsigned short* src = qb + (size_t)(bT + t0 + row) * 2048 + h * D_HEAD + co;
#pragma unroll
        for (int i = 0; i < 4; ++i)
            *(float4*)&Os[row * 136 + co + (i << 3)] = *(const float4*)(src + (i << 3));
        const int q = (w << 4) + c16;
#pragma unroll
        for (int kk = 0; kk < 4; ++kk)
            qfrag[kk] = *(const bf16x8*)&Os[q * 136 + (kk << 5) + (quad << 3)];
    }

    f32x4 acc_o[8];
#pragma unroll
    for (int i = 0; i < 8; ++i) acc_o[i] = (f32x4){0.f, 0.f, 0.f, 0.f};
    float m_r = -1e30f;
    float l_r = 0.f;

    const int nk = (t0 >> 6) + 2;          // causal s-tiles (64 wide)
    const int ntile = nk + (MEM_N >> 6);

    const int sK = tid >> 3, cK = (tid & 7) << 4;   // K staging: s-row, d-chunk (16 u16/thr)
    const int dV = tid >> 2, cV = (tid & 3) << 4;   // V staging: d-row, s-chunk (16 u16/thr)

    float4 kf[2], vf[2];
    {   // prefetch tile 0 (always causal)
        const unsigned short* kp = Krb + (size_t)sK * 128 + cK;
        const unsigned short* vp = Vrb + (size_t)dV * 2048 + cV;
#pragma unroll
        for (int i = 0; i < 2; ++i) {
            kf[i] = *(const float4*)(kp + (i << 3));
            vf[i] = *(const float4*)(vp + (i << 3));
        }
    }

    for (int it = 0; it < ntile; ++it) {
        const int s0 = (it < nk) ? (it << 6) : (T_SEQ + ((it - nk) << 6));
        __syncthreads();   // prev QK/PV reads of Ks/Vts done (also Q frag loads at it=0)
#pragma unroll
        for (int i = 0; i < 2; ++i) {
            *(float4*)&Ks[sK * 136 + cK + (i << 3)] = kf[i];
            *(float4*)&Vts[dV * 72 + cV + (i << 3)] = vf[i];
        }
        if (it + 1 < ntile) {
            const int nx = it + 1;
            const bool nm = nx >= nk;
            const int sl = nm ? ((nx - nk) << 6) : (nx << 6);
            const unsigned short* kp = nm ? memb + (size_t)(sl + sK) * 2048 + h * D_HEAD + cK
                                          : Krb + (size_t)(sl + sK) * 128 + cK;
            const unsigned short* vp = nm ? memt + (size_t)(h * D_HEAD + dV) * 1024 + sl + cV
                                          : Vrb + (size_t)dV * 2048 + sl + cV;
#pragma unroll
            for (int i = 0; i < 2; ++i) {
                kf[i] = *(const float4*)(kp + (i << 3));
                vf[i] = *(const float4*)(vp + (i << 3));
            }
        }
        __syncthreads();   // Ks/Vts staged

        // wave-level skip: tile fully masked for this wave's 16 q rows
        const bool active = (it >= nk) || (s0 <= t0 + (w << 4) + 15);
        if (active) {
            // ---- S^T = K @ Q^T ----
            f32x4 acc_s[4];
#pragma unroll
            for (int nt = 0; nt < 4; ++nt) acc_s[nt] = (f32x4){0.f, 0.f, 0.f, 0.f};
            __builtin_amdgcn_s_setprio(1);
#pragma unroll
            for (int kk = 0; kk < 4; ++kk) {
                bf16x8 ka[4];
#pragma unroll
                for (int nt = 0; nt < 4; ++nt)
                    ka[nt] = *(const bf16x8*)&Ks[(nt * 16 + c16) * 136 + (kk << 5) + (quad << 3)];
#pragma unroll
                for (int nt = 0; nt < 4; ++nt)
                    acc_s[nt] = __builtin_amdgcn_mfma_f32_16x16x32_bf16(ka[nt], qfrag[kk], acc_s[nt], 0, 0, 0);
            }
            __builtin_amdgcn_s_setprio(0);

            // causal boundary mask: s = s0+nt*16+quad*4+r, q = t0+16w+c16
            if (it < nk && (s0 + 63 > t0 + (w << 4))) {
                const int q = t0 + (w << 4) + c16;
#pragma unroll
                for (int nt = 0; nt < 4; ++nt) {
                    const int sbase = s0 + nt * 16 + quad * 4;
#pragma unroll
                    for (int r = 0; r < 4; ++r)
                        if (sbase + r > q) acc_s[nt][r] = -1e30f;
                }
            }

            // ---- online softmax (q in lanes; 2 shfl per reduction) ----
            float m0 = fmaxf(fmaxf(acc_s[0][0], acc_s[0][1]), fmaxf(acc_s[0][2], acc_s[0][3]));
#pragma unroll
            for (int nt = 1; nt < 4; ++nt)
                m0 = fmaxf(m0, fmaxf(fmaxf(acc_s[nt][0], acc_s[nt][1]), fmaxf(acc_s[nt][2], acc_s[nt][3])));
            m0 = fmaxf(m0, __shfl_xor(m0, 16));
            m0 = fmaxf(m0, __shfl_xor(m0, 32));
            const float mn = fmaxf(m_r, m0);
            const float al = __expf(m_r - mn);
            m_r = mn;
            float rs = 0.f;
#pragma unroll
            for (int nt = 0; nt < 4; ++nt)
#pragma unroll
                for (int r = 0; r < 4; ++r) {
                    const float p = __expf(acc_s[nt][r] - mn);
                    acc_s[nt][r] = p;
                    rs += p;
                }
            rs += __shfl_xor(rs, 16);
            rs += __shfl_xor(rs, 32);
            l_r = l_r * al + rs;
#pragma unroll
            for (int dt = 0; dt < 8; ++dt)
#pragma unroll
                for (int r = 0; r < 4; ++r) acc_o[dt][r] *= al;

            // ---- P^T to LDS (wave-private, vectorized, no barrier) ----
            const int qrow = (w << 4) + c16;
#pragma unroll
            for (int nt = 0; nt < 4; ++nt) {
                ushort4 pk;
                pk.x = f2bf(acc_s[nt][0]); pk.y = f2bf(acc_s[nt][1]);
                pk.z = f2bf(acc_s[nt][2]); pk.w = f2bf(acc_s[nt][3]);
                *(ushort4*)&Ps[qrow * 72 + nt * 16 + quad * 4] = pk;
            }

            // ---- O^T += Vt @ P^T ----
            __builtin_amdgcn_s_setprio(1);
#pragma unroll
            for (int ks = 0; ks < 2; ++ks) {
                const bf16x8 pb = *(const bf16x8*)&Ps[qrow * 72 + (ks << 5) + (quad << 3)];
#pragma unroll
                for (int dt = 0; dt < 8; ++dt) {
                    const bf16x8 va = *(const bf16x8*)&Vts[(dt * 16 + c16) * 72 + (ks << 5) + (quad << 3)];
                    acc_o[dt] = __builtin_amdgcn_mfma_f32_16x16x32_bf16(va, pb, acc_o[dt], 0, 0, 0);
                }
            }
            __builtin_amdgcn_s_setprio(0);
        }
    }

    // ---- epilogue: O^T -> row-major via LDS bounce (wave-private), hi+lo ----
    __syncthreads();   // all PV reads of Vts done; Os overlays Ks+Vts
    const float inv = 1.0f / l_r;
    const int row = tid >> 2, co = (tid & 3) << 5;
    unsigned short* gh = attn_h + (size_t)(bT + t0 + row) * 2048 + h * D_HEAD + co;
    unsigned short* gl = attn_l + (size_t)(bT + t0 + row) * 2048 + h * D_HEAD + co;
    const int qrow = (w << 4) + c16;

#pragma unroll
    for (int pass = 0; pass < 2; ++pass) {
#pragma unroll
        for (int dt = 0; dt < 8; ++dt) {
            ushort4 ov;
            unsigned short* po = (unsigned short*)&ov;
#pragma unroll
            for (int r = 0; r < 4; ++r) {
                const float o = acc_o[dt][r] * inv;
                const unsigned int u = __float_as_uint(o);
                if (pass == 0) {
                    po[r] = (unsigned short)(u >> 16);     // truncated hi
                } else {
                    const float lo = o - __uint_as_float(u & 0xFFFF0000u);
                    po[r] = f2bf(lo);
                }
            }
            *(ushort4*)&Os[qrow * 136 + dt * 16 + quad * 4] = ov;
        }
        unsigned short* g = (pass == 0) ? gh : gl;
#pragma unroll
        for (int i = 0; i < 4; ++i)
            *(float4*)(g + (i << 3)) = *(const float4*)&Os[row * 136 + co + (i << 3)];
    }
}

extern "C" void kernel_launch(void* const* d_in, const int* in_sizes, int n_in,
                              void* d_out, int out_size, void* d_ws, size_t ws_size,
                              hipStream_t stream)
{
    const float* x     = (const float*)d_in[0];
    const float* Wqkv  = (const float*)d_in[1];
    const float* bqkv  = (const float*)d_in[2];
    const float* mem   = (const float*)d_in[3];
    const float* Wproj = (const float*)d_in[4];
    const float* bproj = (const float*)d_in[5];
    float* out = (float*)d_out;

    unsigned short* ws16 = (unsigned short*)d_ws;
    unsigned short* WqTh = ws16;                         // 12,582,912
    unsigned short* rgn2 = WqTh + 12582912;              // 12,582,912 (attn_l + WpT tail)
    unsigned short* qb   = rgn2 + 12582912;              //  8,388,608
    unsigned short* Kr   = qb   + 8388608;               //  8,388,608
    unsigned short* Vr   = Kr   + 8388608;               //  8,388,608
    unsigned short* Vrt  = Vr   + 8388608;               //  8,388,608
    unsigned short* memb = Vrt  + 8388608;               //  2,097,152
    unsigned short* memt = memb + 2097152;               //  2,097,152
    unsigned short* attn_h = WqTh;                       // overlay (WqTh dead after gemm1)
    unsigned short* attn_l = rgn2;
    unsigned short* WpTh = rgn2 + 8388608;               //  4,194,304 tail

    split_w_t<<<dim3(96, 32), 256, 0, stream>>>(Wqkv, WqTh, QKV_N);
    split_mem_kernel<<<dim3(32, 16), 256, 0, stream>>>(mem, memb, memt);

    gemm_qkv_mfma<<<dim3(48, 32), 256, 0, stream>>>(x, WqTh, bqkv, qb, Kr, Vr);

    split_w_t<<<dim3(32, 32), 256, 0, stream>>>(Wproj, WpTh, C_DIM);
    transpose_v_kernel<<<dim3(32, 16, 2), 256, 0, stream>>>(Vr, Vrt);

    attn_mfma_kernel<<<dim3(16, 16, 2), 512, 0, stream>>>(qb, Kr, memb, Vrt, memt, attn_h, attn_l);

    gemm_proj_mfma<<<dim3(16, 32), 256, 0, stream>>>(attn_h, attn_l, WpTh, bproj, out);
}

// Round 2
// 678.246 us; speedup vs baseline: 1.0097x; 1.0097x over previous
//
#include <hip/hip_runtime.h>
#include <math.h>

#define T_SEQ  2048
#define C_DIM  2048
#define H_NUM  16
#define D_HEAD 128
#define MEM_N  1024
#define S_ALL  3072
#define QKV_N  6144

typedef __attribute__((ext_vector_type(4))) float f32x4;
typedef __attribute__((ext_vector_type(8))) short bf16x8;
typedef __attribute__((ext_vector_type(8))) unsigned short us8;

__device__ __forceinline__ unsigned short f2bf(float f) {
    unsigned int u = __float_as_uint(f);
    u = (u + 0x7fffu + ((u >> 16) & 1u)) >> 16;   // RNE
    return (unsigned short)u;
}

// async global->LDS, 16B per lane; lds ptr must be wave-uniform (HW adds lane*16)
__device__ __forceinline__ void gload_lds16(const void* g, void* l) {
    __builtin_amdgcn_global_load_lds((const __attribute__((address_space(1))) void*)g,
                                     (__attribute__((address_space(3))) void*)l, 16, 0, 0);
}

// ===== transpose W: [K=2048, N] fp32 -> Th [N][2048] bf16 (RNE) =====
__global__ __launch_bounds__(256, 2)
void split_w_t(const float* __restrict__ W, unsigned short* __restrict__ Th, int N)
{
    __shared__ float tile[64][68];
    const int tid = threadIdx.x;
    const int n0 = blockIdx.x << 6, k0 = blockIdx.y << 6;
    const int r = tid >> 2, c4 = (tid & 3) << 4;
    const float* src = W + (size_t)(k0 + r) * N + n0 + c4;
#pragma unroll
    for (int i = 0; i < 4; ++i)
        *(float4*)&tile[r][c4 + (i << 2)] = *(const float4*)(src + (i << 2));
    __syncthreads();
    unsigned int hi[8];
#pragma unroll
    for (int e = 0; e < 8; ++e) {
        const unsigned int h0 = f2bf(tile[c4 + 2 * e][r]);
        const unsigned int h1 = f2bf(tile[c4 + 2 * e + 1][r]);
        hi[e] = h0 | (h1 << 16);
    }
    unsigned short* dh = Th + (size_t)(n0 + r) * 2048 + k0 + c4;
    *(uint4*)dh       = make_uint4(hi[0], hi[1], hi[2], hi[3]);
    *(uint4*)(dh + 8) = make_uint4(hi[4], hi[5], hi[6], hi[7]);
}

// ===== memory bank: fp32 [1024,2048] -> memb bf16 [1024,2048] + memt bf16 [2048,1024]
__global__ __launch_bounds__(256, 2)
void split_mem_kernel(const float* __restrict__ mem, unsigned short* __restrict__ memb,
                      unsigned short* __restrict__ memt)
{
    __shared__ float tile[64][68];
    const int tid = threadIdx.x;
    const int c0 = blockIdx.x << 6, s0 = blockIdx.y << 6;
    const int r = tid >> 2, c4 = (tid & 3) << 4;
    const float* src = mem + (size_t)(s0 + r) * 2048 + c0 + c4;
    unsigned short* db = memb + (size_t)(s0 + r) * 2048 + c0 + c4;
#pragma unroll
    for (int i = 0; i < 4; ++i) {
        const float4 v = *(const float4*)(src + (i << 2));
        *(float4*)&tile[r][c4 + (i << 2)] = v;
        ushort4 o;
        o.x = f2bf(v.x); o.y = f2bf(v.y); o.z = f2bf(v.z); o.w = f2bf(v.w);
        *(ushort4*)(db + (i << 2)) = o;
    }
    __syncthreads();
    unsigned short* dt = memt + (size_t)(c0 + r) * 1024 + s0 + c4;
#pragma unroll
    for (int i = 0; i < 4; ++i) {
        ushort4 o;
        o.x = f2bf(tile[c4 + (i << 2) + 0][r]);
        o.y = f2bf(tile[c4 + (i << 2) + 1][r]);
        o.z = f2bf(tile[c4 + (i << 2) + 2][r]);
        o.w = f2bf(tile[c4 + (i << 2) + 3][r]);
        *(ushort4*)(dt + (i << 2)) = o;
    }
}

// ===== Vr [b,h,2048,128] bf16 -> Vrt [b,h,128,2048] bf16 =====
__global__ __launch_bounds__(256, 2)
void transpose_v_kernel(const unsigned short* __restrict__ Vr, unsigned short* __restrict__ Vrt)
{
    __shared__ unsigned short Vtmp[64 * 136];
    const int tid = threadIdx.x;
    const int s0 = (int)blockIdx.x << 6;
    const int h = blockIdx.y, b = blockIdx.z;
    const size_t bho = (size_t)(b * H_NUM + h) * (2048 * 128);
    const int sr = tid >> 2, ch = (tid & 3) << 5;
    const unsigned short* vp = Vr + bho + (size_t)(s0 + sr) * 128 + ch;
#pragma unroll
    for (int i = 0; i < 4; ++i)
        *(float4*)&Vtmp[sr * 136 + ch + (i << 3)] = *(const float4*)(vp + (i << 3));
    __syncthreads();
    const int d = tid >> 1, half = tid & 1;
    unsigned short* vd = Vrt + bho + (size_t)d * 2048 + s0 + (half << 5);
#pragma unroll
    for (int c = 0; c < 4; ++c) {
        us8 o;
#pragma unroll
        for (int j = 0; j < 8; ++j)
            o[j] = Vtmp[((half << 5) + (c << 3) + j) * 136 + d];
        *(us8*)(vd + (c << 3)) = o;
    }
}

// ===== GEMM1: qkv = x @ WqT^T + b, 2-term hi/lo MFMA; scatter to qb/Kr/Vr =====
__global__ __launch_bounds__(256, 3)
void gemm_qkv_mfma(const float* __restrict__ x,
                   const unsigned short* __restrict__ Bth,
                   const float* __restrict__ bias,
                   unsigned short* __restrict__ qb, unsigned short* __restrict__ Kr,
                   unsigned short* __restrict__ Vr)
{
    __shared__ unsigned short Ah[128 * 32], Al[128 * 32], Bh[128 * 32];
    const int tid = threadIdx.x;
    const int w = tid >> 6, lane = tid & 63, c16 = lane & 15, quad = lane >> 4;
    const int wm = w & 1, wn = w >> 1;
    const int bm = blockIdx.y << 7, bn = blockIdx.x << 7;

    const int ar = tid >> 1, ak = (tid & 1) << 4;
    const float* pA = x + (size_t)(bm + ar) * 2048 + ak;
    const int wofs = (tid >> 6) << 10;

    f32x4 acc[16];
#pragma unroll
    for (int i = 0; i < 16; ++i) acc[i] = (f32x4){0.f, 0.f, 0.f, 0.f};

    for (int kt = 0; kt < 2048; kt += 32) {
        float4 af[4];
#pragma unroll
        for (int i = 0; i < 4; ++i) af[i] = *(const float4*)(pA + kt + (i << 2));
        __syncthreads();
#pragma unroll
        for (int j = 0; j < 2; ++j) {
            const int c = (j << 8) + tid;
            const size_t go = (size_t)(bn + (c >> 2)) * 2048 + kt + ((c & 3) << 3);
            gload_lds16(Bth + go, (char*)Bh + (j << 12) + wofs);
        }
        const float* f = (const float*)af;
        unsigned int hp[8], lp[8];
#pragma unroll
        for (int e = 0; e < 8; ++e) {
            const unsigned int u0 = __float_as_uint(f[2 * e]), u1 = __float_as_uint(f[2 * e + 1]);
            const float l0 = f[2 * e]     - __uint_as_float(u0 & 0xFFFF0000u);
            const float l1 = f[2 * e + 1] - __uint_as_float(u1 & 0xFFFF0000u);
            hp[e] = (u0 >> 16) | (u1 & 0xFFFF0000u);
            lp[e] = (__float_as_uint(l0) >> 16) | (__float_as_uint(l1) & 0xFFFF0000u);
        }
        *(uint4*)&Ah[ar * 32 + ak]     = make_uint4(hp[0], hp[1], hp[2], hp[3]);
        *(uint4*)&Ah[ar * 32 + ak + 8] = make_uint4(hp[4], hp[5], hp[6], hp[7]);
        *(uint4*)&Al[ar * 32 + ak]     = make_uint4(lp[0], lp[1], lp[2], lp[3]);
        *(uint4*)&Al[ar * 32 + ak + 8] = make_uint4(lp[4], lp[5], lp[6], lp[7]);
        __syncthreads();

        bf16x8 a_h[4], a_l[4];
#pragma unroll
        for (int mt = 0; mt < 4; ++mt) {
            const int ao = (wm * 64 + mt * 16 + c16) * 32 + quad * 8;
            a_h[mt] = *(const bf16x8*)&Ah[ao];
            a_l[mt] = *(const bf16x8*)&Al[ao];
        }
#pragma unroll
        for (int nt = 0; nt < 4; ++nt) {
            const int bo = (wn * 64 + nt * 16 + c16) * 32 + quad * 8;
            const bf16x8 b_h = *(const bf16x8*)&Bh[bo];
#pragma unroll
            for (int mt = 0; mt < 4; ++mt) {
                acc[mt * 4 + nt] = __builtin_amdgcn_mfma_f32_16x16x32_bf16(a_h[mt], b_h, acc[mt * 4 + nt], 0, 0, 0);
                acc[mt * 4 + nt] = __builtin_amdgcn_mfma_f32_16x16x32_bf16(a_l[mt], b_h, acc[mt * 4 + nt], 0, 0, 0);
            }
        }
    }

    const int cls = bn >> 11;
    const float scl = (cls == 0) ? 0.08838834764831845f : 1.0f;
    const int h = (bn & 2047) >> 7;
    float bv[4];
#pragma unroll
    for (int nt = 0; nt < 4; ++nt) bv[nt] = bias[bn + wn * 64 + nt * 16 + c16];
#pragma unroll
    for (int mt = 0; mt < 4; ++mt) {
#pragma unroll
        for (int r = 0; r < 4; ++r) {
            const int rg = bm + wm * 64 + mt * 16 + quad * 4 + r;
            unsigned short* dst;
            if (cls == 0) {
                dst = qb + (size_t)rg * 2048 + bn;
            } else {
                const int bb = rg >> 11, t = rg & 2047;
                dst = (cls == 1 ? Kr : Vr) + (size_t)(bb * H_NUM + h) * (2048 * 128) + (size_t)t * 128;
            }
#pragma unroll
            for (int nt = 0; nt < 4; ++nt)
                dst[wn * 64 + nt * 16 + c16] = f2bf((acc[mt * 4 + nt][r] + bv[nt]) * scl);
        }
    }
}

// ===== GEMM2: out = (attn_h+attn_l) @ WpT^T + b, 2-term hi/lo, fp32 out =====
__global__ __launch_bounds__(256, 3)
void gemm_proj_mfma(const unsigned short* __restrict__ Ahg, const unsigned short* __restrict__ Alg,
                    const unsigned short* __restrict__ Bth,
                    const float* __restrict__ bias, float* __restrict__ out)
{
    __shared__ unsigned short Ah[128 * 32], Al[128 * 32], Bh[128 * 32];
    const int tid = threadIdx.x;
    const int w = tid >> 6, lane = tid & 63, c16 = lane & 15, quad = lane >> 4;
    const int wm = w & 1, wn = w >> 1;
    const int bm = blockIdx.y << 7, bn = blockIdx.x << 7;
    const int wofs = (tid >> 6) << 10;

    f32x4 acc[16];
#pragma unroll
    for (int i = 0; i < 16; ++i) acc[i] = (f32x4){0.f, 0.f, 0.f, 0.f};

    for (int kt = 0; kt < 2048; kt += 32) {
        __syncthreads();
#pragma unroll
        for (int j = 0; j < 2; ++j) {
            const int c = (j << 8) + tid;
            const size_t ga = (size_t)(bm + (c >> 2)) * 2048 + kt + ((c & 3) << 3);
            const size_t gb = (size_t)(bn + (c >> 2)) * 2048 + kt + ((c & 3) << 3);
            gload_lds16(Ahg + ga, (char*)Ah + (j << 12) + wofs);
            gload_lds16(Alg + ga, (char*)Al + (j << 12) + wofs);
            gload_lds16(Bth + gb, (char*)Bh + (j << 12) + wofs);
        }
        __syncthreads();

        bf16x8 a_h[4], a_l[4];
#pragma unroll
        for (int mt = 0; mt < 4; ++mt) {
            const int ao = (wm * 64 + mt * 16 + c16) * 32 + quad * 8;
            a_h[mt] = *(const bf16x8*)&Ah[ao];
            a_l[mt] = *(const bf16x8*)&Al[ao];
        }
#pragma unroll
        for (int nt = 0; nt < 4; ++nt) {
            const int bo = (wn * 64 + nt * 16 + c16) * 32 + quad * 8;
            const bf16x8 b_h = *(const bf16x8*)&Bh[bo];
#pragma unroll
            for (int mt = 0; mt < 4; ++mt) {
                acc[mt * 4 + nt] = __builtin_amdgcn_mfma_f32_16x16x32_bf16(a_h[mt], b_h, acc[mt * 4 + nt], 0, 0, 0);
                acc[mt * 4 + nt] = __builtin_amdgcn_mfma_f32_16x16x32_bf16(a_l[mt], b_h, acc[mt * 4 + nt], 0, 0, 0);
            }
        }
    }

    float bv[4];
#pragma unroll
    for (int nt = 0; nt < 4; ++nt) bv[nt] = bias[bn + wn * 64 + nt * 16 + c16];
#pragma unroll
    for (int mt = 0; mt < 4; ++mt) {
#pragma unroll
        for (int r = 0; r < 4; ++r) {
            const int rg = bm + wm * 64 + mt * 16 + quad * 4 + r;
            float* dst = out + (size_t)rg * 2048 + bn + wn * 64 + c16;
#pragma unroll
            for (int nt = 0; nt < 4; ++nt)
                dst[nt * 16] = acc[mt * 4 + nt][r] + bv[nt];
        }
    }
}

// ============ MFMA flash attention — barrier-free, L2-direct K/V ============
// K/V footprint (58 MB) is L3-resident and mostly L2-resident, so LDS staging
// was pure overhead (m169 lesson). MFMA A-fragments for QK (K rows) and PV
// (Vt rows) are gathered directly from global with per-lane 16B loads
// (16 rows x 64B contiguous per instr — clean L2 pattern). Only wave-private
// LDS remains (Q stage, P bounce, epilogue bounce) -> ZERO __syncthreads,
// no vmcnt(0)/lgkmcnt(0) barrier drains; waves fully decoupled.
// 4 waves x 32 q-rows (2x fragment reuse vs 16q). V gathers are issued
// before the softmax so ~500 VALU cycles hide their L2 latency.
__global__ __launch_bounds__(256, 2)
void attn_mfma_kernel(const unsigned short* __restrict__ qb,
                      const unsigned short* __restrict__ Kr,
                      const unsigned short* __restrict__ memb,
                      const unsigned short* __restrict__ Vrt,
                      const unsigned short* __restrict__ memt,
                      unsigned short* __restrict__ attn_h,
                      unsigned short* __restrict__ attn_l)
{
    __shared__ unsigned short Ps[128 * 72];    // 18,432 B  P^T bounce (wave-private rows)
    __shared__ unsigned short Os[128 * 136];   // 34,816 B  Q stage / epilogue bounce

    const int tid = threadIdx.x;
    const int w = tid >> 6, lane = tid & 63;
    const int c16 = lane & 15, quad = lane >> 4;
    const int bx = blockIdx.x;
    const int h = blockIdx.y, b = blockIdx.z;
    // balance swizzle: co-resident pair (block i, i+256) gets qt x and 15-x
    const int qt = b ? bx : (15 - bx);
    const int t0 = qt << 7;               // 128-row q tile
    const int bT = b * T_SEQ;
    const int bh = b * H_NUM + h;

    const unsigned short* Krb = Kr + (size_t)bh * (2048 * 128);
    const unsigned short* Vrb = Vrt + (size_t)bh * (2048 * 128);
    const unsigned short* membh = memb + h * D_HEAD;
    const unsigned short* memth = memt + (size_t)h * D_HEAD * 1024;

    // ---- stage Q through LDS (wave-private rows), load B-frags to regs ----
    bf16x8 qfrag[2][4];
    {
        const int row = tid >> 1, co = (tid & 1) << 6;
        const unsigned short* src = qb + (size_t)(bT + t0 + row) * 2048 + h * D_HEAD + co;
#pragma unroll
        for (int i = 0; i < 8; ++i)
            *(float4*)&Os[row * 136 + co + (i << 3)] = *(const float4*)(src + (i << 3));
#pragma unroll
        for (int qi = 0; qi < 2; ++qi) {
            const int q = (w << 5) + qi * 16 + c16;
#pragma unroll
            for (int kk = 0; kk < 4; ++kk)
                qfrag[qi][kk] = *(const bf16x8*)&Os[q * 136 + (kk << 5) + (quad << 3)];
        }
    }

    f32x4 acc_o[2][8];
#pragma unroll
    for (int qi = 0; qi < 2; ++qi)
#pragma unroll
        for (int i = 0; i < 8; ++i) acc_o[qi][i] = (f32x4){0.f, 0.f, 0.f, 0.f};
    float m_r[2] = {-1e30f, -1e30f};
    float l_r[2] = {0.f, 0.f};

    const int nk = (t0 >> 6) + 2;          // causal s-tiles (64 wide)
    const int ntile = nk + (MEM_N >> 6);
    const int qmax_w = t0 + (w << 5) + 31; // this wave's last q row

    for (int it = 0; it < ntile; ++it) {
        const bool mem_t = it >= nk;
        const int sl = mem_t ? ((it - nk) << 6) : (it << 6);  // local s within source
        if (!mem_t && sl > qmax_w) continue;   // fully-masked tile for this wave
        const int s0 = mem_t ? (T_SEQ + sl) : sl;             // logical s

        // source geometry for this tile
        const unsigned short* kb = mem_t ? membh + (size_t)sl * 2048 : Krb + (size_t)sl * 128;
        const int kst = mem_t ? 2048 : 128;
        const unsigned short* vb = mem_t ? memth + sl : Vrb + sl;
        const int vst = mem_t ? 1024 : 2048;

        // ---- gather K A-frags from L2 and compute S^T = K @ Q^T ----
        f32x4 acc_s[4][2];
#pragma unroll
        for (int nt = 0; nt < 4; ++nt)
#pragma unroll
            for (int qi = 0; qi < 2; ++qi) acc_s[nt][qi] = (f32x4){0.f, 0.f, 0.f, 0.f};

        bf16x8 ka[4][4];
#pragma unroll
        for (int nt = 0; nt < 4; ++nt) {
            const unsigned short* kr = kb + (size_t)(nt * 16 + c16) * kst + (quad << 3);
#pragma unroll
            for (int kk = 0; kk < 4; ++kk)
                ka[nt][kk] = *(const bf16x8*)(kr + (kk << 5));
        }
        __builtin_amdgcn_s_setprio(1);
#pragma unroll
        for (int kk = 0; kk < 4; ++kk)
#pragma unroll
            for (int nt = 0; nt < 4; ++nt)
#pragma unroll
                for (int qi = 0; qi < 2; ++qi)
                    acc_s[nt][qi] = __builtin_amdgcn_mfma_f32_16x16x32_bf16(ka[nt][kk], qfrag[qi][kk], acc_s[nt][qi], 0, 0, 0);
        __builtin_amdgcn_s_setprio(0);

        // ---- gather V A-frags now; softmax VALU below hides their latency ----
        bf16x8 va[8][2];
#pragma unroll
        for (int dt = 0; dt < 8; ++dt) {
            const unsigned short* vr = vb + (size_t)(dt * 16 + c16) * vst + (quad << 3);
#pragma unroll
            for (int ks = 0; ks < 2; ++ks)
                va[dt][ks] = *(const bf16x8*)(vr + (ks << 5));
        }

        // causal boundary mask: s = s0+nt*16+quad*4+r, q = t0+32w+16qi+c16
        if (!mem_t && (s0 + 63 > t0 + (w << 5))) {
#pragma unroll
            for (int nt = 0; nt < 4; ++nt) {
                const int sbase = s0 + nt * 16 + quad * 4;
#pragma unroll
                for (int qi = 0; qi < 2; ++qi) {
                    const int q = t0 + (w << 5) + qi * 16 + c16;
#pragma unroll
                    for (int r = 0; r < 4; ++r)
                        if (sbase + r > q) acc_s[nt][qi][r] = -1e30f;
                }
            }
        }

        // ---- online softmax (q in lanes; 2 shfl per reduction) ----
        float mx[2], al[2], rs[2];
#pragma unroll
        for (int qi = 0; qi < 2; ++qi) {
            float m0 = fmaxf(fmaxf(acc_s[0][qi][0], acc_s[0][qi][1]), fmaxf(acc_s[0][qi][2], acc_s[0][qi][3]));
#pragma unroll
            for (int nt = 1; nt < 4; ++nt)
                m0 = fmaxf(m0, fmaxf(fmaxf(acc_s[nt][qi][0], acc_s[nt][qi][1]), fmaxf(acc_s[nt][qi][2], acc_s[nt][qi][3])));
            m0 = fmaxf(m0, __shfl_xor(m0, 16));
            m0 = fmaxf(m0, __shfl_xor(m0, 32));
            mx[qi] = m0;
        }
#pragma unroll
        for (int qi = 0; qi < 2; ++qi) {
            const float mn = fmaxf(m_r[qi], mx[qi]);
            al[qi] = __expf(m_r[qi] - mn);
            m_r[qi] = mn;
            float s = 0.f;
#pragma unroll
            for (int nt = 0; nt < 4; ++nt)
#pragma unroll
                for (int r = 0; r < 4; ++r) {
                    const float p = __expf(acc_s[nt][qi][r] - mn);
                    acc_s[nt][qi][r] = p;
                    s += p;
                }
            rs[qi] = s;
        }
#pragma unroll
        for (int qi = 0; qi < 2; ++qi) {
            rs[qi] += __shfl_xor(rs[qi], 16);
            rs[qi] += __shfl_xor(rs[qi], 32);
            l_r[qi] = l_r[qi] * al[qi] + rs[qi];
#pragma unroll
            for (int dt = 0; dt < 8; ++dt)
#pragma unroll
                for (int r = 0; r < 4; ++r) acc_o[qi][dt][r] *= al[qi];
        }

        // ---- P^T to LDS (wave-private, vectorized, no barrier) ----
#pragma unroll
        for (int qi = 0; qi < 2; ++qi) {
            const int q = (w << 5) + qi * 16 + c16;
#pragma unroll
            for (int nt = 0; nt < 4; ++nt) {
                ushort4 pk;
                pk.x = f2bf(acc_s[nt][qi][0]); pk.y = f2bf(acc_s[nt][qi][1]);
                pk.z = f2bf(acc_s[nt][qi][2]); pk.w = f2bf(acc_s[nt][qi][3]);
                *(ushort4*)&Ps[q * 72 + nt * 16 + quad * 4] = pk;
            }
        }

        // ---- O^T += Vt @ P^T ----
        __builtin_amdgcn_s_setprio(1);
#pragma unroll
        for (int ks = 0; ks < 2; ++ks) {
            bf16x8 pb[2];
#pragma unroll
            for (int qi = 0; qi < 2; ++qi)
                pb[qi] = *(const bf16x8*)&Ps[((w << 5) + qi * 16 + c16) * 72 + (ks << 5) + (quad << 3)];
#pragma unroll
            for (int dt = 0; dt < 8; ++dt) {
                acc_o[0][dt] = __builtin_amdgcn_mfma_f32_16x16x32_bf16(va[dt][ks], pb[0], acc_o[0][dt], 0, 0, 0);
                acc_o[1][dt] = __builtin_amdgcn_mfma_f32_16x16x32_bf16(va[dt][ks], pb[1], acc_o[1][dt], 0, 0, 0);
            }
        }
        __builtin_amdgcn_s_setprio(0);
    }

    // ---- epilogue: O^T -> row-major via LDS bounce (wave-private), hi+lo ----
    const float inv[2] = {1.0f / l_r[0], 1.0f / l_r[1]};
    const int row = tid >> 1, co = (tid & 1) << 6;
    unsigned short* gh = attn_h + (size_t)(bT + t0 + row) * 2048 + h * D_HEAD + co;
    unsigned short* gl = attn_l + (size_t)(bT + t0 + row) * 2048 + h * D_HEAD + co;

#pragma unroll
    for (int pass = 0; pass < 2; ++pass) {
#pragma unroll
        for (int qi = 0; qi < 2; ++qi) {
            const int q = (w << 5) + qi * 16 + c16;
#pragma unroll
            for (int dt = 0; dt < 8; ++dt) {
                ushort4 ov;
                unsigned short* po = (unsigned short*)&ov;
#pragma unroll
                for (int r = 0; r < 4; ++r) {
                    const float o = acc_o[qi][dt][r] * inv[qi];
                    const unsigned int u = __float_as_uint(o);
                    if (pass == 0) {
                        po[r] = (unsigned short)(u >> 16);     // truncated hi
                    } else {
                        const float lo = o - __uint_as_float(u & 0xFFFF0000u);
                        po[r] = f2bf(lo);
                    }
                }
                *(ushort4*)&Os[q * 136 + dt * 16 + quad * 4] = ov;
            }
        }
        unsigned short* g = (pass == 0) ? gh : gl;
#pragma unroll
        for (int i = 0; i < 8; ++i)
            *(float4*)(g + (i << 3)) = *(const float4*)&Os[row * 136 + co + (i << 3)];
    }
}

extern "C" void kernel_launch(void* const* d_in, const int* in_sizes, int n_in,
                              void* d_out, int out_size, void* d_ws, size_t ws_size,
                              hipStream_t stream)
{
    const float* x     = (const float*)d_in[0];
    const float* Wqkv  = (const float*)d_in[1];
    const float* bqkv  = (const float*)d_in[2];
    const float* mem   = (const float*)d_in[3];
    const float* Wproj = (const float*)d_in[4];
    const float* bproj = (const float*)d_in[5];
    float* out = (float*)d_out;

    unsigned short* ws16 = (unsigned short*)d_ws;
    unsigned short* WqTh = ws16;                         // 12,582,912
    unsigned short* rgn2 = WqTh + 12582912;              // 12,582,912 (attn_l + WpT tail)
    unsigned short* qb   = rgn2 + 12582912;              //  8,388,608
    unsigned short* Kr   = qb   + 8388608;               //  8,388,608
    unsigned short* Vr   = Kr   + 8388608;               //  8,388,608
    unsigned short* Vrt  = Vr   + 8388608;               //  8,388,608
    unsigned short* memb = Vrt  + 8388608;               //  2,097,152
    unsigned short* memt = memb + 2097152;               //  2,097,152
    unsigned short* attn_h = WqTh;                       // overlay (WqTh dead after gemm1)
    unsigned short* attn_l = rgn2;
    unsigned short* WpTh = rgn2 + 8388608;               //  4,194,304 tail

    split_w_t<<<dim3(96, 32), 256, 0, stream>>>(Wqkv, WqTh, QKV_N);
    split_mem_kernel<<<dim3(32, 16), 256, 0, stream>>>(mem, memb, memt);

    gemm_qkv_mfma<<<dim3(48, 32), 256, 0, stream>>>(x, WqTh, bqkv, qb, Kr, Vr);

    split_w_t<<<dim3(32, 32), 256, 0, stream>>>(Wproj, WpTh, C_DIM);
    transpose_v_kernel<<<dim3(32, 16, 2), 256, 0, stream>>>(Vr, Vrt);

    attn_mfma_kernel<<<dim3(16, 16, 2), 256, 0, stream>>>(qb, Kr, memb, Vrt, memt, attn_h, attn_l);

    gemm_proj_mfma<<<dim3(16, 32), 256, 0, stream>>>(attn_h, attn_l, WpTh, bproj, out);
}